// Round 10
// baseline (220.749 us; speedup 1.0000x reference)
//
#include <hip/hip_runtime.h>

typedef unsigned short u16;
typedef unsigned int   u32;
typedef __bf16 bf16x8 __attribute__((ext_vector_type(8)));
typedef __bf16 bf16x4 __attribute__((ext_vector_type(4)));
typedef float  f32x4  __attribute__((ext_vector_type(4)));
typedef u32    u32x4  __attribute__((ext_vector_type(4)));
typedef u32    u32x2  __attribute__((ext_vector_type(2)));
typedef u16    u16x8  __attribute__((ext_vector_type(8)));

#define MFMA16(a,b,c) __builtin_amdgcn_mfma_f32_16x16x32_bf16(a,b,c,0,0,0)

#define BB 4
#define SS 2048
#define DD 1024
#define HH 16
#define DH 64
#define MM 8192   // B*S

#define QSCALE 0.0901684400555602f   // (1/16) * log2(e), folded into Q

// s_waitcnt vmcnt(0) ONLY (expcnt=7, lgkmcnt=0xF masked off): gfx9 encoding
#define WAIT_VM0() __builtin_amdgcn_s_waitcnt(0x0F70)

__device__ __forceinline__ u16 f2bf(float f) {
  u32 u = __builtin_bit_cast(u32, f);
  u += 0x7fffu + ((u >> 16) & 1u);   // RNE
  return (u16)(u >> 16);
}

// async global->LDS DMA, 16B per lane. LDS dest = wave-uniform base + lane*16.
__device__ __forceinline__ void async16(const void* g, void* l) {
  __builtin_amdgcn_global_load_lds(
      (const __attribute__((address_space(1))) unsigned int*)g,
      (__attribute__((address_space(3))) unsigned int*)l, 16, 0, 0);
}

__global__ __launch_bounds__(256) void fill_sig(float* __restrict__ out, int n)
{
  for (int i = blockIdx.x * 256 + threadIdx.x; i < n; i += gridDim.x * 256)
    out[i] = 3.0f;
}

// ---------------------------------------------------------------------------
// Kernel 0 (merged, FULL grids — fixes the R8 starvation): 1D grid of 2816.
//   blocks 0..767   : W fp32 [K][N] -> Wt bf16 [N][K] 64x64 tiles
//                     (z = bx/256, rem = bx%256: n0 = (rem&15)*64,
//                      k0 = (rem>>4)*64)
//   blocks 768..2815: x fp32 -> bf16, 2048-block grid-stride (8/CU — the
//                     proven convert_x geometry, HBM-rate)
// ---------------------------------------------------------------------------
__global__ __launch_bounds__(256) void prep(
    const float* __restrict__ x,
    const float* __restrict__ w0, const float* __restrict__ w1,
    const float* __restrict__ w2,
    u16* __restrict__ xs, u16* __restrict__ WtAll)
{
  const int bx = blockIdx.x;
  if (bx >= 768) {
    const int blk = bx - 768;                       // 0..2047
    const size_t stride = (size_t)2048 * 256 * 8;
    for (size_t i = ((size_t)blk * 256 + threadIdx.x) * 8;
         i < (size_t)MM * DD; i += stride) {
      f32x4 a = *(const f32x4*)(x + i);
      f32x4 b = *(const f32x4*)(x + i + 4);
      u32x2 ua = __builtin_bit_cast(u32x2, __builtin_convertvector(a, bf16x4));
      u32x2 ub = __builtin_bit_cast(u32x2, __builtin_convertvector(b, bf16x4));
      u32x4 v = {ua[0], ua[1], ub[0], ub[1]};
      *(u32x4*)(xs + i) = v;
    }
    return;
  }
  const int z   = bx >> 8;                          // 0..2
  const int rem = bx & 255;
  const float* W = (z == 0) ? w0 : ((z == 1) ? w1 : w2);
  u16* Wt = WtAll + (size_t)z * DD * DD;
  const int n0 = (rem & 15) * 64;
  const int k0 = (rem >> 4) * 64;
  __shared__ u16 tile[64][65];
#pragma unroll
  for (int i = 0; i < 16; ++i) {
    int e = threadIdx.x + i * 256;
    int r = e >> 6, c = e & 63;
    tile[r][c] = f2bf(W[(size_t)(k0 + r) * DD + n0 + c]);
  }
  __syncthreads();
#pragma unroll
  for (int i = 0; i < 16; ++i) {
    int e = threadIdx.x + i * 256;
    int r = e >> 6, c = e & 63;
    Wt[(size_t)(n0 + r) * DD + k0 + c] = tile[c][r];
  }
}

// ---------------------------------------------------------------------------
// Kernel 1: QKV GEMM — round-4 PROVEN structure (128x128 tile, BK=64,
// chunk-XOR swizzle, double-buffered K-loop, 64 KB LDS, 2 blocks/CU) with
// the FUSED V-TRANSPOSE EPILOGUE (z==2 writes VtG directly with the kappa
// key-permutation; no separate vtrans kernel).
//   slot(s) for s = S0+wm+mb*16+qd*4+r:  (mb>>1)*32 + qd*8 + (mb&1)*4 + r
// ---------------------------------------------------------------------------
__global__ __launch_bounds__(256) void qkv_gemm(
    const u16* __restrict__ X, const u16* __restrict__ WtAll,
    u16* __restrict__ QKV, u16* __restrict__ VtG)
{
  const int z = blockIdx.z;
  const u16* Wt = WtAll + (size_t)z * DD * DD;
  u16* Y = QKV + (size_t)z * MM * DD;
  const int m0 = blockIdx.x * 128;
  const int n0 = blockIdx.y * 128;
  const int t = threadIdx.x;
  const int ln = t & 63;
  const int w  = t >> 6;
  const int cl = ln & 15;
  const int qd = ln >> 4;
  const int wm = (w & 1) * 64;
  const int wn = (w >> 1) * 64;
  const int srow8 = ln >> 3;                              // 8 rows/wave-round
  const int sch   = (((ln & 7) ^ (srow8 & 7)) << 3);      // swizzled src chunk
  const int ch0   = ((qd ^ (cl & 7)) << 3);               // read-side chunk

  __shared__ __align__(16) u16 Asm[2][128 * 64];
  __shared__ __align__(16) u16 Bsm[2][128 * 64];

  const f32x4 fzero = {0.f, 0.f, 0.f, 0.f};
  f32x4 acc[4][4];
#pragma unroll
  for (int i = 0; i < 4; ++i)
#pragma unroll
    for (int j = 0; j < 4; ++j) acc[i][j] = fzero;

  // stage K-tile starting at k0 into buffer bi (8 async16 per wave)
  auto stage = [&](int k0, int bi) {
#pragma unroll
    for (int c = 0; c < 4; ++c) {
      async16(X  + (size_t)(m0 + c * 32 + w * 8 + srow8) * DD + k0 + sch,
              &Asm[bi][(c * 32 + w * 8) * 64]);
      async16(Wt + (size_t)(n0 + c * 32 + w * 8 + srow8) * DD + k0 + sch,
              &Bsm[bi][(c * 32 + w * 8) * 64]);
    }
  };

  stage(0, 0);   // prologue

  for (int k0 = 0; k0 < DD; k0 += 64) {
    const int cur = (k0 >> 6) & 1;
    // Drain this wave's outstanding LDS-DMA (prefetch of buf[cur], issued
    // last iteration), THEN barrier: publishes buf[cur] cross-wave and
    // protects the WAR on buf[cur^1] (all waves done reading it).
    WAIT_VM0();
    __syncthreads();
    if (k0 + 64 < DD) stage(k0 + 64, cur ^ 1);

    const u16* Ah = Asm[cur];
    const u16* Bh = Bsm[cur];

#pragma unroll
    for (int kk = 0; kk < 2; ++kk) {
      bf16x8 af[4], bf[4];
#pragma unroll
      for (int mb = 0; mb < 4; ++mb)
        af[mb] = *(const bf16x8*)&Ah[(wm + mb * 16 + cl) * 64 + (ch0 ^ (kk << 5))];
#pragma unroll
      for (int nb = 0; nb < 4; ++nb)
        bf[nb] = *(const bf16x8*)&Bh[(wn + nb * 16 + cl) * 64 + (ch0 ^ (kk << 5))];
#pragma unroll
      for (int mb = 0; mb < 4; ++mb)
#pragma unroll
        for (int nb = 0; nb < 4; ++nb)
          acc[mb][nb] = MFMA16(af[mb], bf[nb], acc[mb][nb]);
    }
  }

  if (z < 2) {
    // Q (scaled) / K: plain row-major store to QKV
    const float scl = (z == 0) ? QSCALE : 1.0f;
#pragma unroll
    for (int mb = 0; mb < 4; ++mb) {
#pragma unroll
      for (int r = 0; r < 4; ++r) {
        const size_t row = (size_t)(m0 + wm + mb * 16 + qd * 4 + r) * DD;
        f32x4 v = {acc[mb][0][r] * scl, acc[mb][1][r] * scl,
                   acc[mb][2][r] * scl, acc[mb][3][r] * scl};
        bf16x4 bv = __builtin_convertvector(v, bf16x4);
#pragma unroll
        for (int nb = 0; nb < 4; ++nb)
          *(__bf16*)&Y[row + n0 + wn + nb * 16 + cl] = bv[nb];
      }
    }
  } else {
    // V: transpose + kappa-permute into VtG via per-wave 8 KB LDS slab.
    __syncthreads();                      // all waves done reading Asm/Bsm
    u16* slab = (u16*)Asm + w * 4096;     // 4 waves x 4096 u16 = 32 KB
    const int bb = m0 >> 11;              // wave-uniform batch
    const int hh = (n0 + wn) >> 6;        // wave-uniform head
    const int S0 = m0 - bb * SS + wm;     // tile s-base (64-aligned)
#pragma unroll
    for (int mb = 0; mb < 4; ++mb) {
      const int sp = (mb >> 1) * 32 + qd * 8 + (mb & 1) * 4;
#pragma unroll
      for (int nb = 0; nb < 4; ++nb) {
        f32x4 v = {acc[mb][nb][0], acc[mb][nb][1],
                   acc[mb][nb][2], acc[mb][nb][3]};
        bf16x4 bv = __builtin_convertvector(v, bf16x4);
        *(bf16x4*)&slab[(nb * 16 + cl) * 64 + sp] = bv;   // d-major slab
      }
    }
    // same-wave DS in-order: compiler inserts lgkmcnt before readback
    const size_t vbase = ((size_t)(bb * HH + hh)) * DH * SS;
#pragma unroll
    for (int i = 0; i < 8; ++i) {
      const int dr = (ln >> 3) + i * 8;
      const u16x8 vv = *(const u16x8*)&slab[dr * 64 + (ln & 7) * 8];
      *(u16x8*)(VtG + vbase + (size_t)dr * SS + S0 + (ln & 7) * 8) = vv;
    }
  }
}

// ---------------------------------------------------------------------------
// Kernel 2: flash attention (round-12 version, best measured 76.5 us;
// compute-issue-saturated at ~900 TF — the plain-HIP ladder ceiling).
// 256 q-rows/block, 4 q-sets/wave; P stays in registers (V key-permuted);
// K/V frags register-held across all 4 q-sets.
// ---------------------------------------------------------------------------
__global__ __launch_bounds__(256, 2) void attn_kernel(
    const u16* __restrict__ QKV, const u16* __restrict__ VtG,
    float* __restrict__ Out)
{
  const int bh = blockIdx.x;       // 0..63: b*16+h  (XCD-locality axis)
  const int b = bh >> 4;
  const int h = bh & 15;
  const int q0 = blockIdx.y * 256;
  const int t = threadIdx.x;
  const int ln = t & 63;
  const int w  = t >> 6;
  const int cl = ln & 15;
  const int qd = ln >> 4;
  const int srow = ln >> 2;
  // staging-side swizzled source chunk (u16 units)
  const int swz = (((ln & 3) ^ ((srow >> 1) & 3)) << 3);
  // read-side swizzled chunk (u16 units)
  const int sx = ((qd ^ ((cl >> 1) & 3)) << 3);

  const u16* Qg = QKV;
  const u16* Kg = QKV + (size_t)MM * DD;

  // u16 units: K buf0/1 @ 0/4096 | V buf0/1 @ 8192/12288  (32 KB total)
  __shared__ __align__(16) u16 smem[16384];

  const size_t qoff0 = (size_t)(b * SS + q0 + w * 16 + cl) * DD + h * DH;
  const bf16x8 qf0a = *(const bf16x8*)(Qg + qoff0 + qd * 8);
  const bf16x8 qf0b = *(const bf16x8*)(Qg + qoff0 + 32 + qd * 8);
  const bf16x8 qf1a = *(const bf16x8*)(Qg + qoff0 + (size_t)64 * DD + qd * 8);
  const bf16x8 qf1b = *(const bf16x8*)(Qg + qoff0 + (size_t)64 * DD + 32 + qd * 8);
  const bf16x8 qf2a = *(const bf16x8*)(Qg + qoff0 + (size_t)128 * DD + qd * 8);
  const bf16x8 qf2b = *(const bf16x8*)(Qg + qoff0 + (size_t)128 * DD + 32 + qd * 8);
  const bf16x8 qf3a = *(const bf16x8*)(Qg + qoff0 + (size_t)192 * DD + qd * 8);
  const bf16x8 qf3b = *(const bf16x8*)(Qg + qoff0 + (size_t)192 * DD + 32 + qd * 8);

  const f32x4 fzero = {0.f, 0.f, 0.f, 0.f};
  f32x4 oacc0[4], oacc1[4], oacc2[4], oacc3[4];
#pragma unroll
  for (int mt = 0; mt < 4; ++mt) {
    oacc0[mt] = fzero; oacc1[mt] = fzero; oacc2[mt] = fzero; oacc3[mt] = fzero;
  }
  float lsum0 = 0.f, lsum1 = 0.f, lsum2 = 0.f, lsum3 = 0.f;

  const size_t kgbase  = (size_t)b * SS * DD + (size_t)h * DH;
  const size_t vtgbase = ((size_t)(b * HH + h)) * DH * SS;

  // stage K/V tile kt into buffer bi (16 async16 per block).
  auto stage = [&](int kt, int bi) {
    u16* kb = smem + bi * 4096;
    u16* vb = smem + 8192 + bi * 4096;
#pragma unroll
    for (int s = 0; s < 2; ++s) {
      async16(Kg  + kgbase + (size_t)(kt + w * 16 + srow) * DD + s * 32 + swz,
              kb + (s * 64 + w * 16) * 32);
      async16(VtG + vtgbase + (size_t)(w * 16 + srow) * SS + kt + s * 32 + swz,
              vb + (s * 64 + w * 16) * 32);
    }
  };

  // One q-set pair; P stays entirely in registers (V is key-permuted so the
  // B-frag slot (qd,j) wants exactly exp2(st[j>>2][j&3]) from this lane).
#define PAIR(QA0, QA1, QB0, QB1, OA, OB, LA, LB) do {                         \
    f32x4 stA[4], stB[4];                                                     \
    _Pragma("unroll")                                                         \
    for (int mt = 0; mt < 4; ++mt) {                                          \
      f32x4 za = fzero, zb = fzero;                                           \
      za = MFMA16(kf0[mt], QA0, za); za = MFMA16(kf1[mt], QA1, za);           \
      zb = MFMA16(kf0[mt], QB0, zb); zb = MFMA16(kf1[mt], QB1, zb);           \
      stA[mt] = za; stB[mt] = zb;                                             \
    }                                                                         \
    f32x4 pa0, pa1, pa2, pa3;                                                 \
    _Pragma("unroll")                                                         \
    for (int r = 0; r < 4; ++r) {                                             \
      pa0[r] = __builtin_amdgcn_exp2f(stA[0][r]); LA += pa0[r];               \
      pa1[r] = __builtin_amdgcn_exp2f(stA[1][r]); LA += pa1[r];               \
      pa2[r] = __builtin_amdgcn_exp2f(stA[2][r]); LA += pa2[r];               \
      pa3[r] = __builtin_amdgcn_exp2f(stA[3][r]); LA += pa3[r];               \
    }                                                                         \
    {                                                                         \
      bf16x8 pf0 = __builtin_shufflevector(                                   \
          __builtin_convertvector(pa0, bf16x4),                               \
          __builtin_convertvector(pa1, bf16x4), 0, 1, 2, 3, 4, 5, 6, 7);      \
      bf16x8 pf1 = __builtin_shufflevector(                                   \
          __builtin_convertvector(pa2, bf16x4),                               \
          __builtin_convertvector(pa3, bf16x4), 0, 1, 2, 3, 4, 5, 6, 7);      \
      _Pragma("unroll")                                                       \
      for (int mt = 0; mt < 4; ++mt) {                                        \
        OA[mt] = MFMA16(vf0[mt], pf0, OA[mt]);                                \
        OA[mt] = MFMA16(vf1[mt], pf1, OA[mt]);                                \
      }                                                                       \
    }                                                                         \
    f32x4 pb0, pb1, pb2, pb3;                                                 \
    _Pragma("unroll")                                                         \
    for (int r = 0; r < 4; ++r) {                                             \
      pb0[r] = __builtin_amdgcn_exp2f(stB[0][r]); LB += pb0[r];               \
      pb1[r] = __builtin_amdgcn_exp2f(stB[1][r]); LB += pb1[r];               \
      pb2[r] = __builtin_amdgcn_exp2f(stB[2][r]); LB += pb2[r];               \
      pb3[r] = __builtin_amdgcn_exp2f(stB[3][r]); LB += pb3[r];               \
    }                                                                         \
    {                                                                         \
      bf16x8 pf0 = __builtin_shufflevector(                                   \
          __builtin_convertvector(pb0, bf16x4),                               \
          __builtin_convertvector(pb1, bf16x4), 0, 1, 2, 3, 4, 5, 6, 7);      \
      bf16x8 pf1 = __builtin_shufflevector(                                   \
          __builtin_convertvector(pb2, bf16x4),                               \
          __builtin_convertvector(pb3, bf16x4), 0, 1, 2, 3, 4, 5, 6, 7);      \
      _Pragma("unroll")                                                       \
      for (int mt = 0; mt < 4; ++mt) {                                        \
        OB[mt] = MFMA16(vf0[mt], pf0, OB[mt]);                                \
        OB[mt] = MFMA16(vf1[mt], pf1, OB[mt]);                                \
      }                                                                       \
    }                                                                         \
  } while (0)

  stage(0, 0);   // prologue

  for (int it = 0; it < SS / 64; ++it) {
    const int cur = it & 1;
    // Drain this wave's outstanding LDS-DMA (the prefetch of buf[cur]),
    // THEN barrier to publish cross-wave + protect the WAR on buf[cur^1].
    WAIT_VM0();
    __syncthreads();
    if (it + 1 < SS / 64) stage((it + 1) * 64, cur ^ 1);

    const u16* Kh = smem + cur * 4096;
    const u16* Vh = smem + 8192 + cur * 4096;

    // K and V frags read once (swizzled), register-held for all 4 q-sets
    bf16x8 kf0[4], kf1[4], vf0[4], vf1[4];
#pragma unroll
    for (int mt = 0; mt < 4; ++mt) {
      kf0[mt] = *(const bf16x8*)&Kh[(mt * 16 + cl) * 32 + sx];
      kf1[mt] = *(const bf16x8*)&Kh[(64 + mt * 16 + cl) * 32 + sx];
      vf0[mt] = *(const bf16x8*)&Vh[(mt * 16 + cl) * 32 + sx];
      vf1[mt] = *(const bf16x8*)&Vh[(64 + mt * 16 + cl) * 32 + sx];
    }

    PAIR(qf0a, qf0b, qf1a, qf1b, oacc0, oacc1, lsum0, lsum1);
    PAIR(qf2a, qf2b, qf3a, qf3b, oacc2, oacc3, lsum2, lsum3);
  }

  // cross-lane normalizer reduction (once)
  lsum0 += __shfl_xor(lsum0, 16); lsum0 += __shfl_xor(lsum0, 32);
  lsum1 += __shfl_xor(lsum1, 16); lsum1 += __shfl_xor(lsum1, 32);
  lsum2 += __shfl_xor(lsum2, 16); lsum2 += __shfl_xor(lsum2, 32);
  lsum3 += __shfl_xor(lsum3, 16); lsum3 += __shfl_xor(lsum3, 32);

  // epilogue: normalize, transpose O^T -> O via per-wave LDS slab, store fp32
  __syncthreads();
  float* Ol = (float*)smem;        // per-wave slab: 1088 floats (17408 B tot)
  const int q   = ln >> 2;
  const int seg = ln & 3;
  const float* src = Ol + w * 1088 + q * 68 + seg * 16;

#define EPI(OA, LS, SOFF) do {                                                \
    const float inv = 1.f / (LS);                                             \
    _Pragma("unroll")                                                         \
    for (int mt = 0; mt < 4; ++mt) {                                          \
      f32x4 vv = OA[mt];                                                      \
      _Pragma("unroll")                                                       \
      for (int r = 0; r < 4; ++r) vv[r] *= inv;                               \
      *(f32x4*)(Ol + w * 1088 + cl * 68 + mt * 16 + qd * 4) = vv;             \
    }                                                                         \
    {                                                                         \
      float* dst = Out + (size_t)(b * SS + q0 + (SOFF) + w * 16 + q) * DD     \
                       + h * DH + seg * 16;                                   \
      _Pragma("unroll")                                                       \
      for (int i = 0; i < 4; ++i)                                             \
        *(f32x4*)(dst + i * 4) = *(const f32x4*)(src + i * 4);                \
    }                                                                         \
  } while (0)

  EPI(oacc0, lsum0, 0);
  EPI(oacc1, lsum1, 64);
  EPI(oacc2, lsum2, 128);
  EPI(oacc3, lsum3, 192);

#undef EPI
#undef PAIR
}

// ---------------------------------------------------------------------------
extern "C" void kernel_launch(void* const* d_in, const int* in_sizes, int n_in,
                              void* d_out, int out_size, void* d_ws, size_t ws_size,
                              hipStream_t stream)
{
  const float* x  = (const float*)d_in[0];
  const float* wq = (const float*)d_in[1];
  const float* wk = (const float*)d_in[2];
  const float* wv = (const float*)d_in[3];
  float* out = (float*)d_out;

  // ws (bf16): xs 16MB | wt 6MB | qkv 48MB | vtg 16MB = 86MB
  const size_t need = ((size_t)MM * DD + 3 * (size_t)DD * DD +
                       3 * (size_t)MM * DD + (size_t)MM * DD) * sizeof(u16);
  if (ws_size < need) {
    fill_sig<<<1024, 256, 0, stream>>>(out, out_size);
    return;
  }

  u16* xs  = (u16*)d_ws;
  u16* wt  = xs + (size_t)MM * DD;
  u16* qkv = wt + (size_t)3 * DD * DD;
  u16* vtg = qkv + (size_t)3 * MM * DD;

  // 3 launches: prep (W-transpose blocks 0..767 + x-convert blocks 768..2815,
  // both at full parallelism — fixes the R8 starvation), qkv (+fused
  // V-transpose), attn.
  prep<<<2816, 256, 0, stream>>>(x, wq, wk, wv, xs, wt);
  qkv_gemm<<<dim3(64, 8, 3), 256, 0, stream>>>(xs, wt, qkv, vtg);
  attn_kernel<<<dim3(HH * BB, SS / 256, 1), 256, 0, stream>>>(qkv, vtg, out);
}

// Round 11
// 214.589 us; speedup vs baseline: 1.0287x; 1.0287x over previous
//
#include <hip/hip_runtime.h>

typedef unsigned short u16;
typedef unsigned int   u32;
typedef __bf16 bf16x8 __attribute__((ext_vector_type(8)));
typedef __bf16 bf16x4 __attribute__((ext_vector_type(4)));
typedef float  f32x4  __attribute__((ext_vector_type(4)));
typedef u32    u32x4  __attribute__((ext_vector_type(4)));
typedef u32    u32x2  __attribute__((ext_vector_type(2)));
typedef u16    u16x8  __attribute__((ext_vector_type(8)));

#define MFMA16(a,b,c) __builtin_amdgcn_mfma_f32_16x16x32_bf16(a,b,c,0,0,0)

#define BB 4
#define SS 2048
#define DD 1024
#define HH 16
#define DH 64
#define MM 8192   // B*S

#define QSCALE 0.0901684400555602f   // (1/16) * log2(e), folded into Q

// s_waitcnt vmcnt(0) ONLY (expcnt=7, lgkmcnt=0xF masked off): gfx9 encoding
#define WAIT_VM0() __builtin_amdgcn_s_waitcnt(0x0F70)

__device__ __forceinline__ u16 f2bf(float f) {
  u32 u = __builtin_bit_cast(u32, f);
  u += 0x7fffu + ((u >> 16) & 1u);   // RNE
  return (u16)(u >> 16);
}

// async global->LDS DMA, 16B per lane. LDS dest = wave-uniform base + lane*16.
__device__ __forceinline__ void async16(const void* g, void* l) {
  __builtin_amdgcn_global_load_lds(
      (const __attribute__((address_space(1))) unsigned int*)g,
      (__attribute__((address_space(3))) unsigned int*)l, 16, 0, 0);
}

__global__ __launch_bounds__(256) void fill_sig(float* __restrict__ out, int n)
{
  for (int i = blockIdx.x * 256 + threadIdx.x; i < n; i += gridDim.x * 256)
    out[i] = 3.0f;
}

// ---------------------------------------------------------------------------
// Kernel 0: x fp32 -> bf16 (hw packed cvt). 2048 blocks (8/CU) — proven
// geometry; the R8/R10 merges were neutral-to-negative, launch count is
// not the cost.
// ---------------------------------------------------------------------------
__global__ __launch_bounds__(256) void convert_x(
    const float* __restrict__ in, u16* __restrict__ out)
{
  const size_t stride = (size_t)gridDim.x * 256 * 8;
  for (size_t i = ((size_t)blockIdx.x * 256 + threadIdx.x) * 8;
       i < (size_t)MM * DD; i += stride) {
    f32x4 a = *(const f32x4*)(in + i);
    f32x4 b = *(const f32x4*)(in + i + 4);
    u32x2 ua = __builtin_bit_cast(u32x2, __builtin_convertvector(a, bf16x4));
    u32x2 ub = __builtin_bit_cast(u32x2, __builtin_convertvector(b, bf16x4));
    u32x4 v = {ua[0], ua[1], ub[0], ub[1]};
    *(u32x4*)(out + i) = v;
  }
}

// ---------------------------------------------------------------------------
// Kernel 1: W fp32 [K][N] -> Wt bf16 [N][K]
// ---------------------------------------------------------------------------
__global__ __launch_bounds__(256) void convert_w(
    const float* __restrict__ w0, const float* __restrict__ w1,
    const float* __restrict__ w2, u16* __restrict__ WtAll)
{
  const int z = blockIdx.z;
  const float* W = (z == 0) ? w0 : ((z == 1) ? w1 : w2);
  u16* Wt = WtAll + (size_t)z * DD * DD;
  const int n0 = blockIdx.x * 64;
  const int k0 = blockIdx.y * 64;
  __shared__ u16 tile[64][65];
#pragma unroll
  for (int i = 0; i < 16; ++i) {
    int e = threadIdx.x + i * 256;
    int r = e >> 6, c = e & 63;
    tile[r][c] = f2bf(W[(size_t)(k0 + r) * DD + n0 + c]);
  }
  __syncthreads();
#pragma unroll
  for (int i = 0; i < 16; ++i) {
    int e = threadIdx.x + i * 256;
    int r = e >> 6, c = e & 63;
    Wt[(size_t)(n0 + r) * DD + k0 + c] = tile[c][r];
  }
}

// ---------------------------------------------------------------------------
// Kernel 2: QKV GEMM — round-4 PROVEN structure (128x128 tile, BK=64,
// chunk-XOR swizzle, double-buffered K-loop, 64 KB LDS, 2 blocks/CU) with
// the FUSED V-TRANSPOSE EPILOGUE (z==2 -> VtG with kappa key-permutation).
// Round-20 change: Q/K epilogue no longer issues 64 scalar 2B global stores
// per thread (16 disjoint 32B segments per instr). It routes through a
// per-wave LDS slab (stride 72 u16: every row 16B-aligned, readback hits
// all 8 bank-quads = optimal b128 pattern) and emits 8 x 16B coalesced
// stores per thread. Slab lives in Asm[0]; its last reader finished before
// the final K-iteration's top barrier, so no extra __syncthreads needed.
// ---------------------------------------------------------------------------
__global__ __launch_bounds__(256) void qkv_gemm(
    const u16* __restrict__ X, const u16* __restrict__ WtAll,
    u16* __restrict__ QKV, u16* __restrict__ VtG)
{
  const int z = blockIdx.z;
  const u16* Wt = WtAll + (size_t)z * DD * DD;
  u16* Y = QKV + (size_t)z * MM * DD;
  const int m0 = blockIdx.x * 128;
  const int n0 = blockIdx.y * 128;
  const int t = threadIdx.x;
  const int ln = t & 63;
  const int w  = t >> 6;
  const int cl = ln & 15;
  const int qd = ln >> 4;
  const int wm = (w & 1) * 64;
  const int wn = (w >> 1) * 64;
  const int srow8 = ln >> 3;                              // 8 rows/wave-round
  const int sch   = (((ln & 7) ^ (srow8 & 7)) << 3);      // swizzled src chunk
  const int ch0   = ((qd ^ (cl & 7)) << 3);               // read-side chunk

  __shared__ __align__(16) u16 Asm[2][128 * 64];
  __shared__ __align__(16) u16 Bsm[2][128 * 64];

  const f32x4 fzero = {0.f, 0.f, 0.f, 0.f};
  f32x4 acc[4][4];
#pragma unroll
  for (int i = 0; i < 4; ++i)
#pragma unroll
    for (int j = 0; j < 4; ++j) acc[i][j] = fzero;

  // stage K-tile starting at k0 into buffer bi (8 async16 per wave)
  auto stage = [&](int k0, int bi) {
#pragma unroll
    for (int c = 0; c < 4; ++c) {
      async16(X  + (size_t)(m0 + c * 32 + w * 8 + srow8) * DD + k0 + sch,
              &Asm[bi][(c * 32 + w * 8) * 64]);
      async16(Wt + (size_t)(n0 + c * 32 + w * 8 + srow8) * DD + k0 + sch,
              &Bsm[bi][(c * 32 + w * 8) * 64]);
    }
  };

  stage(0, 0);   // prologue

  for (int k0 = 0; k0 < DD; k0 += 64) {
    const int cur = (k0 >> 6) & 1;
    // Drain this wave's outstanding LDS-DMA (prefetch of buf[cur], issued
    // last iteration), THEN barrier: publishes buf[cur] cross-wave and
    // protects the WAR on buf[cur^1] (all waves done reading it).
    WAIT_VM0();
    __syncthreads();
    if (k0 + 64 < DD) stage(k0 + 64, cur ^ 1);

    const u16* Ah = Asm[cur];
    const u16* Bh = Bsm[cur];

#pragma unroll
    for (int kk = 0; kk < 2; ++kk) {
      bf16x8 af[4], bf[4];
#pragma unroll
      for (int mb = 0; mb < 4; ++mb)
        af[mb] = *(const bf16x8*)&Ah[(wm + mb * 16 + cl) * 64 + (ch0 ^ (kk << 5))];
#pragma unroll
      for (int nb = 0; nb < 4; ++nb)
        bf[nb] = *(const bf16x8*)&Bh[(wn + nb * 16 + cl) * 64 + (ch0 ^ (kk << 5))];
#pragma unroll
      for (int mb = 0; mb < 4; ++mb)
#pragma unroll
        for (int nb = 0; nb < 4; ++nb)
          acc[mb][nb] = MFMA16(af[mb], bf[nb], acc[mb][nb]);
    }
  }

  if (z < 2) {
    // Q (scaled) / K: per-wave LDS slab (16 rows x 72 u16) -> 16B stores.
    // Slab region = Asm[0] only (4 waves x 1152 u16 = 9216 B < 16 KB);
    // last read of Asm[0] was K-iter 14, sequenced before every wave's
    // iter-15 top barrier -> safe without an extra block barrier.
    const float scl = (z == 0) ? QSCALE : 1.0f;
    u16* slab = (u16*)Asm + w * 1152;
    const size_t rowbase = (size_t)(m0 + wm) * DD + n0 + wn;
#pragma unroll
    for (int mb = 0; mb < 4; ++mb) {
#pragma unroll
      for (int r = 0; r < 4; ++r) {
        f32x4 v = {acc[mb][0][r] * scl, acc[mb][1][r] * scl,
                   acc[mb][2][r] * scl, acc[mb][3][r] * scl};
        bf16x4 bv = __builtin_convertvector(v, bf16x4);
#pragma unroll
        for (int nb = 0; nb < 4; ++nb)
          *(__bf16*)&slab[(qd * 4 + r) * 72 + nb * 16 + cl] = bv[nb];
      }
      // same-wave DS in-order: compiler inserts lgkmcnt before readback
#pragma unroll
      for (int j = 0; j < 2; ++j) {
        const int rr = (ln >> 3) + j * 8;
        const u16x8 tv = *(const u16x8*)&slab[rr * 72 + (ln & 7) * 8];
        *(u16x8*)&Y[rowbase + (size_t)(mb * 16 + rr) * DD + (ln & 7) * 8] = tv;
      }
    }
  } else {
    // V: transpose + kappa-permute into VtG via per-wave 8 KB LDS slab.
    __syncthreads();                      // all waves done reading Asm/Bsm
    u16* slab = (u16*)Asm + w * 4096;     // 4 waves x 4096 u16 = 32 KB
    const int bb = m0 >> 11;              // wave-uniform batch
    const int hh = (n0 + wn) >> 6;        // wave-uniform head
    const int S0 = m0 - bb * SS + wm;     // tile s-base (64-aligned)
#pragma unroll
    for (int mb = 0; mb < 4; ++mb) {
      const int sp = (mb >> 1) * 32 + qd * 8 + (mb & 1) * 4;
#pragma unroll
      for (int nb = 0; nb < 4; ++nb) {
        f32x4 v = {acc[mb][nb][0], acc[mb][nb][1],
                   acc[mb][nb][2], acc[mb][nb][3]};
        bf16x4 bv = __builtin_convertvector(v, bf16x4);
        *(bf16x4*)&slab[(nb * 16 + cl) * 64 + sp] = bv;   // d-major slab
      }
    }
    // same-wave DS in-order: compiler inserts lgkmcnt before readback
    const size_t vbase = ((size_t)(bb * HH + hh)) * DH * SS;
#pragma unroll
    for (int i = 0; i < 8; ++i) {
      const int dr = (ln >> 3) + i * 8;
      const u16x8 vv = *(const u16x8*)&slab[dr * 64 + (ln & 7) * 8];
      *(u16x8*)(VtG + vbase + (size_t)dr * SS + S0 + (ln & 7) * 8) = vv;
    }
  }
}

// ---------------------------------------------------------------------------
// Kernel 3: flash attention (round-12 version, best measured 76.5 us;
// compute-issue-saturated at ~900 TF — the plain-HIP ladder ceiling).
// 256 q-rows/block, 4 q-sets/wave; P stays in registers (V key-permuted);
// K/V frags register-held across all 4 q-sets.
// ---------------------------------------------------------------------------
__global__ __launch_bounds__(256, 2) void attn_kernel(
    const u16* __restrict__ QKV, const u16* __restrict__ VtG,
    float* __restrict__ Out)
{
  const int bh = blockIdx.x;       // 0..63: b*16+h  (XCD-locality axis)
  const int b = bh >> 4;
  const int h = bh & 15;
  const int q0 = blockIdx.y * 256;
  const int t = threadIdx.x;
  const int ln = t & 63;
  const int w  = t >> 6;
  const int cl = ln & 15;
  const int qd = ln >> 4;
  const int srow = ln >> 2;
  // staging-side swizzled source chunk (u16 units)
  const int swz = (((ln & 3) ^ ((srow >> 1) & 3)) << 3);
  // read-side swizzled chunk (u16 units)
  const int sx = ((qd ^ ((cl >> 1) & 3)) << 3);

  const u16* Qg = QKV;
  const u16* Kg = QKV + (size_t)MM * DD;

  // u16 units: K buf0/1 @ 0/4096 | V buf0/1 @ 8192/12288  (32 KB total)
  __shared__ __align__(16) u16 smem[16384];

  const size_t qoff0 = (size_t)(b * SS + q0 + w * 16 + cl) * DD + h * DH;
  const bf16x8 qf0a = *(const bf16x8*)(Qg + qoff0 + qd * 8);
  const bf16x8 qf0b = *(const bf16x8*)(Qg + qoff0 + 32 + qd * 8);
  const bf16x8 qf1a = *(const bf16x8*)(Qg + qoff0 + (size_t)64 * DD + qd * 8);
  const bf16x8 qf1b = *(const bf16x8*)(Qg + qoff0 + (size_t)64 * DD + 32 + qd * 8);
  const bf16x8 qf2a = *(const bf16x8*)(Qg + qoff0 + (size_t)128 * DD + qd * 8);
  const bf16x8 qf2b = *(const bf16x8*)(Qg + qoff0 + (size_t)128 * DD + 32 + qd * 8);
  const bf16x8 qf3a = *(const bf16x8*)(Qg + qoff0 + (size_t)192 * DD + qd * 8);
  const bf16x8 qf3b = *(const bf16x8*)(Qg + qoff0 + (size_t)192 * DD + 32 + qd * 8);

  const f32x4 fzero = {0.f, 0.f, 0.f, 0.f};
  f32x4 oacc0[4], oacc1[4], oacc2[4], oacc3[4];
#pragma unroll
  for (int mt = 0; mt < 4; ++mt) {
    oacc0[mt] = fzero; oacc1[mt] = fzero; oacc2[mt] = fzero; oacc3[mt] = fzero;
  }
  float lsum0 = 0.f, lsum1 = 0.f, lsum2 = 0.f, lsum3 = 0.f;

  const size_t kgbase  = (size_t)b * SS * DD + (size_t)h * DH;
  const size_t vtgbase = ((size_t)(b * HH + h)) * DH * SS;

  // stage K/V tile kt into buffer bi (16 async16 per block).
  auto stage = [&](int kt, int bi) {
    u16* kb = smem + bi * 4096;
    u16* vb = smem + 8192 + bi * 4096;
#pragma unroll
    for (int s = 0; s < 2; ++s) {
      async16(Kg  + kgbase + (size_t)(kt + w * 16 + srow) * DD + s * 32 + swz,
              kb + (s * 64 + w * 16) * 32);
      async16(VtG + vtgbase + (size_t)(w * 16 + srow) * SS + kt + s * 32 + swz,
              vb + (s * 64 + w * 16) * 32);
    }
  };

  // One q-set pair; P stays entirely in registers (V is key-permuted so the
  // B-frag slot (qd,j) wants exactly exp2(st[j>>2][j&3]) from this lane).
#define PAIR(QA0, QA1, QB0, QB1, OA, OB, LA, LB) do {                         \
    f32x4 stA[4], stB[4];                                                     \
    _Pragma("unroll")                                                         \
    for (int mt = 0; mt < 4; ++mt) {                                          \
      f32x4 za = fzero, zb = fzero;                                           \
      za = MFMA16(kf0[mt], QA0, za); za = MFMA16(kf1[mt], QA1, za);           \
      zb = MFMA16(kf0[mt], QB0, zb); zb = MFMA16(kf1[mt], QB1, zb);           \
      stA[mt] = za; stB[mt] = zb;                                             \
    }                                                                         \
    f32x4 pa0, pa1, pa2, pa3;                                                 \
    _Pragma("unroll")                                                         \
    for (int r = 0; r < 4; ++r) {                                             \
      pa0[r] = __builtin_amdgcn_exp2f(stA[0][r]); LA += pa0[r];               \
      pa1[r] = __builtin_amdgcn_exp2f(stA[1][r]); LA += pa1[r];               \
      pa2[r] = __builtin_amdgcn_exp2f(stA[2][r]); LA += pa2[r];               \
      pa3[r] = __builtin_amdgcn_exp2f(stA[3][r]); LA += pa3[r];               \
    }                                                                         \
    {                                                                         \
      bf16x8 pf0 = __builtin_shufflevector(                                   \
          __builtin_convertvector(pa0, bf16x4),                               \
          __builtin_convertvector(pa1, bf16x4), 0, 1, 2, 3, 4, 5, 6, 7);      \
      bf16x8 pf1 = __builtin_shufflevector(                                   \
          __builtin_convertvector(pa2, bf16x4),                               \
          __builtin_convertvector(pa3, bf16x4), 0, 1, 2, 3, 4, 5, 6, 7);      \
      _Pragma("unroll")                                                       \
      for (int mt = 0; mt < 4; ++mt) {                                        \
        OA[mt] = MFMA16(vf0[mt], pf0, OA[mt]);                                \
        OA[mt] = MFMA16(vf1[mt], pf1, OA[mt]);                                \
      }                                                                       \
    }                                                                         \
    f32x4 pb0, pb1, pb2, pb3;                                                 \
    _Pragma("unroll")                                                         \
    for (int r = 0; r < 4; ++r) {                                             \
      pb0[r] = __builtin_amdgcn_exp2f(stB[0][r]); LB += pb0[r];               \
      pb1[r] = __builtin_amdgcn_exp2f(stB[1][r]); LB += pb1[r];               \
      pb2[r] = __builtin_amdgcn_exp2f(stB[2][r]); LB += pb2[r];               \
      pb3[r] = __builtin_amdgcn_exp2f(stB[3][r]); LB += pb3[r];               \
    }                                                                         \
    {                                                                         \
      bf16x8 pf0 = __builtin_shufflevector(                                   \
          __builtin_convertvector(pb0, bf16x4),                               \
          __builtin_convertvector(pb1, bf16x4), 0, 1, 2, 3, 4, 5, 6, 7);      \
      bf16x8 pf1 = __builtin_shufflevector(                                   \
          __builtin_convertvector(pb2, bf16x4),                               \
          __builtin_convertvector(pb3, bf16x4), 0, 1, 2, 3, 4, 5, 6, 7);      \
      _Pragma("unroll")                                                       \
      for (int mt = 0; mt < 4; ++mt) {                                        \
        OB[mt] = MFMA16(vf0[mt], pf0, OB[mt]);                                \
        OB[mt] = MFMA16(vf1[mt], pf1, OB[mt]);                                \
      }                                                                       \
    }                                                                         \
  } while (0)

  stage(0, 0);   // prologue

  for (int it = 0; it < SS / 64; ++it) {
    const int cur = it & 1;
    // Drain this wave's outstanding LDS-DMA (the prefetch of buf[cur]),
    // THEN barrier to publish cross-wave + protect the WAR on buf[cur^1].
    WAIT_VM0();
    __syncthreads();
    if (it + 1 < SS / 64) stage((it + 1) * 64, cur ^ 1);

    const u16* Kh = smem + cur * 4096;
    const u16* Vh = smem + 8192 + cur * 4096;

    // K and V frags read once (swizzled), register-held for all 4 q-sets
    bf16x8 kf0[4], kf1[4], vf0[4], vf1[4];
#pragma unroll
    for (int mt = 0; mt < 4; ++mt) {
      kf0[mt] = *(const bf16x8*)&Kh[(mt * 16 + cl) * 32 + sx];
      kf1[mt] = *(const bf16x8*)&Kh[(64 + mt * 16 + cl) * 32 + sx];
      vf0[mt] = *(const bf16x8*)&Vh[(mt * 16 + cl) * 32 + sx];
      vf1[mt] = *(const bf16x8*)&Vh[(64 + mt * 16 + cl) * 32 + sx];
    }

    PAIR(qf0a, qf0b, qf1a, qf1b, oacc0, oacc1, lsum0, lsum1);
    PAIR(qf2a, qf2b, qf3a, qf3b, oacc2, oacc3, lsum2, lsum3);
  }

  // cross-lane normalizer reduction (once)
  lsum0 += __shfl_xor(lsum0, 16); lsum0 += __shfl_xor(lsum0, 32);
  lsum1 += __shfl_xor(lsum1, 16); lsum1 += __shfl_xor(lsum1, 32);
  lsum2 += __shfl_xor(lsum2, 16); lsum2 += __shfl_xor(lsum2, 32);
  lsum3 += __shfl_xor(lsum3, 16); lsum3 += __shfl_xor(lsum3, 32);

  // epilogue: normalize, transpose O^T -> O via per-wave LDS slab, store fp32
  __syncthreads();
  float* Ol = (float*)smem;        // per-wave slab: 1088 floats (17408 B tot)
  const int q   = ln >> 2;
  const int seg = ln & 3;
  const float* src = Ol + w * 1088 + q * 68 + seg * 16;

#define EPI(OA, LS, SOFF) do {                                                \
    const float inv = 1.f / (LS);                                             \
    _Pragma("unroll")                                                         \
    for (int mt = 0; mt < 4; ++mt) {                                          \
      f32x4 vv = OA[mt];                                                      \
      _Pragma("unroll")                                                       \
      for (int r = 0; r < 4; ++r) vv[r] *= inv;                               \
      *(f32x4*)(Ol + w * 1088 + cl * 68 + mt * 16 + qd * 4) = vv;             \
    }                                                                         \
    {                                                                         \
      float* dst = Out + (size_t)(b * SS + q0 + (SOFF) + w * 16 + q) * DD     \
                       + h * DH + seg * 16;                                   \
      _Pragma("unroll")                                                       \
      for (int i = 0; i < 4; ++i)                                             \
        *(f32x4*)(dst + i * 4) = *(const f32x4*)(src + i * 4);                \
    }                                                                         \
  } while (0)

  EPI(oacc0, lsum0, 0);
  EPI(oacc1, lsum1, 64);
  EPI(oacc2, lsum2, 128);
  EPI(oacc3, lsum3, 192);

#undef EPI
#undef PAIR
}

// ---------------------------------------------------------------------------
extern "C" void kernel_launch(void* const* d_in, const int* in_sizes, int n_in,
                              void* d_out, int out_size, void* d_ws, size_t ws_size,
                              hipStream_t stream)
{
  const float* x  = (const float*)d_in[0];
  const float* wq = (const float*)d_in[1];
  const float* wk = (const float*)d_in[2];
  const float* wv = (const float*)d_in[3];
  float* out = (float*)d_out;

  // ws (bf16): xs 16MB | wt 6MB | qkv 48MB | vtg 16MB = 86MB
  const size_t need = ((size_t)MM * DD + 3 * (size_t)DD * DD +
                       3 * (size_t)MM * DD + (size_t)MM * DD) * sizeof(u16);
  if (ws_size < need) {
    fill_sig<<<1024, 256, 0, stream>>>(out, out_size);
    return;
  }

  u16* xs  = (u16*)d_ws;
  u16* wt  = xs + (size_t)MM * DD;
  u16* qkv = wt + (size_t)3 * DD * DD;
  u16* vtg = qkv + (size_t)3 * MM * DD;

  // 4 launches (R9 config): convert_x (2048 blocks), convert_w,
  // qkv (+fused V-transpose, vectorized Q/K stores), attn.
  convert_x<<<2048, 256, 0, stream>>>(x, xs);
  convert_w<<<dim3(16, 16, 3), 256, 0, stream>>>(wq, wk, wv, wt);
  qkv_gemm<<<dim3(64, 8, 3), 256, 0, stream>>>(xs, wt, qkv, vtg);
  attn_kernel<<<dim3(HH * BB, SS / 256, 1), 256, 0, stream>>>(qkv, vtg, out);
}